// Round 11
// baseline (206.386 us; speedup 1.0000x reference)
//
#include <hip/hip_runtime.h>
#include <hip/hip_bf16.h>
#include <math.h>

#define B_ 4
#define S_ 2048
#define H_ 512
#define HEADS_ 8
#define DK_ 64
#define NROWS_ (B_*S_)          // 8192
#define LN_EPS_ 1e-5f
#define NEG_INF_ -1e30f
// Q pre-scale: 1/sqrt(DK) * log2(e)  (softmax done in exp2 domain)
#define QSCALE_ (0.125f * 1.44269504088896f)

typedef short s8v __attribute__((ext_vector_type(8)));   // 8 bf16 (4 VGPRs)
typedef short s4v __attribute__((ext_vector_type(4)));   // 4 bf16 (2 VGPRs)
typedef float f4v __attribute__((ext_vector_type(4)));

typedef __attribute__((address_space(1))) unsigned int gu32_t;
typedef __attribute__((address_space(3))) unsigned int lu32_t;

__device__ __forceinline__ unsigned short f2bf(float f) {
    unsigned int u = __float_as_uint(f);
    u += 0x7FFFu + ((u >> 16) & 1u);     // round-to-nearest-even
    return (unsigned short)(u >> 16);
}

__device__ __forceinline__ float bf2f(unsigned short u) {
    return __uint_as_float((unsigned int)u << 16);
}

__device__ __forceinline__ s4v pk4bf(float a, float b, float c, float d) {
    union { __hip_bfloat162 h[2]; s4v v; } u;
    u.h[0] = __float22bfloat162_rn(float2{a, b});
    u.h[1] = __float22bfloat162_rn(float2{c, d});
    return u.v;
}

// ---------------------------------------------------------------------------
// Kernel 1: PREP = LayerNorm (blocks 0..2047) + weight transpose (2048..3071).
// ---------------------------------------------------------------------------
__global__ __launch_bounds__(256) void prep_kernel(
        const float* __restrict__ x, const float* __restrict__ gamma,
        const float* __restrict__ beta, const int* __restrict__ mask,
        const float* __restrict__ Wq, const float* __restrict__ Wk,
        const float* __restrict__ Wv, const float* __restrict__ Wo,
        unsigned short* __restrict__ xnb, float* __restrict__ mb,
        unsigned short* __restrict__ Wt) {
    int bx = blockIdx.x;
    if (bx < 2048) {                       // ---------------- LayerNorm
        int row  = bx * 4 + (threadIdx.x >> 6);
        int lane = threadIdx.x & 63;
        const float4* xr = (const float4*)(x + (size_t)row * H_ + lane * 8);
        float4 a = xr[0], d = xr[1];
        float s  = (a.x + a.y) + (a.z + a.w) + (d.x + d.y) + (d.z + d.w);
        float ss = (a.x*a.x + a.y*a.y) + (a.z*a.z + a.w*a.w)
                 + (d.x*d.x + d.y*d.y) + (d.z*d.z + d.w*d.w);
        #pragma unroll
        for (int i = 1; i < 64; i <<= 1) {
            s  += __shfl_xor(s, i, 64);
            ss += __shfl_xor(ss, i, 64);
        }
        float mu  = s * (1.f / 512.f);
        float var = ss * (1.f / 512.f) - mu * mu;
        float rstd = rsqrtf(var + LN_EPS_);
        if (lane == 0) mb[row] = mask[row] ? 0.f : NEG_INF_;
        const float4* gp = (const float4*)(gamma + lane * 8);
        const float4* bp = (const float4*)(beta + lane * 8);
        float4 g0 = gp[0], g1 = gp[1], b0 = bp[0], b1 = bp[1];
        float4 y0, y1;
        y0.x = (a.x - mu) * rstd * g0.x + b0.x;
        y0.y = (a.y - mu) * rstd * g0.y + b0.y;
        y0.z = (a.z - mu) * rstd * g0.z + b0.z;
        y0.w = (a.w - mu) * rstd * g0.w + b0.w;
        y1.x = (d.x - mu) * rstd * g1.x + b1.x;
        y1.y = (d.y - mu) * rstd * g1.y + b1.y;
        y1.z = (d.z - mu) * rstd * g1.z + b1.z;
        y1.w = (d.w - mu) * rstd * g1.w + b1.w;
        union { s4v h[2]; s8v v; } pk;
        pk.h[0] = pk4bf(y0.x, y0.y, y0.z, y0.w);
        pk.h[1] = pk4bf(y1.x, y1.y, y1.z, y1.w);
        *(s8v*)(xnb + (size_t)row * H_ + lane * 8) = pk.v;
    } else {                               // ---------------- weight transpose
        __shared__ float tile[32][33];
        int wid = bx - 2048;
        const float* src;
        int ld, drow, k0, c0;
        float scale = 1.f;
        if (wid < 768) {
            int z = wid >> 5, rem = wid & 31;
            int cx = rem & 1, ky = rem >> 1;
            k0 = ky * 32; c0 = cx * 32;
            int zw = z >> 3, head = z & 7;
            const float* W = (zw == 0) ? Wq : (zw == 1) ? Wk : Wv;
            if (zw == 0) scale = QSCALE_;
            src = W + (size_t)head * H_ * DK_;
            ld = DK_;
            drow = zw * 512 + head * 64;
        } else {
            int rem = wid - 768;
            int cx = rem & 15, ky = rem >> 4;
            k0 = ky * 32; c0 = cx * 32;
            src = Wo; ld = H_; drow = 1536;
        }
        int tx = threadIdx.x & 31, ty = threadIdx.x >> 5;
        #pragma unroll
        for (int i = 0; i < 4; i++)
            tile[ty * 4 + i][tx] = src[(size_t)(k0 + ty * 4 + i) * ld + c0 + tx];
        __syncthreads();
        #pragma unroll
        for (int i = 0; i < 4; i++) {
            int cc = ty * 4 + i;
            Wt[(size_t)(drow + c0 + cc) * 512 + k0 + tx] = f2bf(tile[tx][cc] * scale);
        }
    }
}

// ---------------------------------------------------------------------------
// Shared MFMA GEMM tile loop. Depth-2 pipeline, 3 LDS buffer pairs (48 KB),
// vmcnt(8) steady state (R5). Total-neutral vs R3 but harmless; kept.
// ---------------------------------------------------------------------------
__device__ __forceinline__ void gemm_tile(
        const unsigned short* __restrict__ A,
        const unsigned short* __restrict__ Bt,
        int r0, int j0, f4v acc[4][4]) {
    __shared__ unsigned short As[3 * 128 * 32];   // [buf][row][k32], 8 KB each
    __shared__ unsigned short Bs[3 * 128 * 32];
    int t = threadIdx.x;
    int wv = t >> 6, L = t & 63, c = L & 15, g = L >> 4;
    int m_base = (wv & 1) * 64, n_base = (wv >> 1) * 64;
    #pragma unroll
    for (int i = 0; i < 4; i++)
        #pragma unroll
        for (int j = 0; j < 4; j++) acc[i][j] = (f4v){0.f, 0.f, 0.f, 0.f};

    // wave wv stages 32 rows (16B units uu = wv*128 + i*64 + L): 4 loads/wave
    auto stage = [&](int buf, int k0) {
        #pragma unroll
        for (int i = 0; i < 2; i++) {
            int uu = wv * 128 + i * 64 + L;
            int row = uu >> 2, k16 = uu & 3;
            __builtin_amdgcn_global_load_lds(
                (const gu32_t*)(A + (size_t)(r0 + row) * 512 + k0 + k16 * 8),
                (lu32_t*)(As + buf * 4096 + (size_t)(wv * 128 + i * 64) * 8), 16, 0, 0);
            __builtin_amdgcn_global_load_lds(
                (const gu32_t*)(Bt + (size_t)(j0 + row) * 512 + k0 + k16 * 8),
                (lu32_t*)(Bs + buf * 4096 + (size_t)(wv * 128 + i * 64) * 8), 16, 0, 0);
        }
    };

    auto compute = [&](int buf) {
        s8v a[4], b[4];
        #pragma unroll
        for (int i = 0; i < 4; i++)
            a[i] = *(const s8v*)(As + buf * 4096 + (size_t)(m_base + i * 16 + c) * 32 + g * 8);
        #pragma unroll
        for (int j = 0; j < 4; j++)
            b[j] = *(const s8v*)(Bs + buf * 4096 + (size_t)(n_base + j * 16 + c) * 32 + g * 8);
        #pragma unroll
        for (int i = 0; i < 4; i++)
            #pragma unroll
            for (int j = 0; j < 4; j++)
                acc[i][j] = __builtin_amdgcn_mfma_f32_16x16x32_bf16(
                    a[i], b[j], acc[i][j], 0, 0, 0);
    };

    stage(0, 0);
    stage(1, 32);
    #pragma unroll
    for (int s = 0; s < 14; ++s) {          // halves 0..13; stage halves 2..15
        stage((s + 2) % 3, (s + 2) * 32);
        __asm__ volatile("s_waitcnt vmcnt(8)" ::: "memory");  // own half-s done
        __builtin_amdgcn_s_barrier();                         // all half-s done
        compute(s % 3);
        __builtin_amdgcn_s_barrier();       // all reads of buf[s%3] done
    }
    __asm__ volatile("s_waitcnt vmcnt(4)" ::: "memory");      // half 14 done
    __builtin_amdgcn_s_barrier();
    compute(14 % 3);
    __builtin_amdgcn_s_barrier();
    __asm__ volatile("s_waitcnt vmcnt(0)" ::: "memory");      // half 15 done
    __builtin_amdgcn_s_barrier();
    compute(15 % 3);
}

// ---------------------------------------------------------------------------
// Kernel 2: QKV GEMM (epilogues unchanged).
// ---------------------------------------------------------------------------
__global__ __launch_bounds__(256) void qkv_gemm(
        const unsigned short* __restrict__ xnb,
        const unsigned short* __restrict__ Wt,
        unsigned short* __restrict__ Qb, unsigned short* __restrict__ Kf,
        unsigned short* __restrict__ Vf) {
    f4v acc[4][4];
    int t = threadIdx.x;
    int wv = t >> 6, L = t & 63, c = L & 15, g = L >> 4;
    int rb = wv & 1, cb = wv >> 1;
    if (blockIdx.x < 8) {
        int m0 = blockIdx.x * 128, n0 = blockIdx.y * 128;
        gemm_tile(Wt, xnb, m0, n0, acc);
        int R0 = m0 + rb * 64;            // Wt-row base (64-aligned, one head)
        int C0 = n0 + cb * 64;            // token base (64-aligned)
        int hd = (R0 >> 6) & 7;
        int b  = C0 >> 11, srow0 = C0 & 2047;
        size_t bhbase = (size_t)(b * HEADS_ + hd) * S_ * DK_;
        if (R0 < 512) {                   // ---- Q: row-major (token, dk)
            #pragma unroll
            for (int msub = 0; msub < 4; msub++) {
                int dk4 = msub * 16 + g * 4;
                #pragma unroll
                for (int nsub = 0; nsub < 4; nsub++) {
                    int tok = srow0 + nsub * 16 + c;
                    s4v v = pk4bf(acc[msub][nsub][0], acc[msub][nsub][1],
                                  acc[msub][nsub][2], acc[msub][nsub][3]);
                    *(s4v*)(Qb + bhbase + (size_t)tok * DK_ + dk4) = v;
                }
            }
        } else {                          // ---- K: fragment-major
            unsigned short* dst = Kf + bhbase + (size_t)(srow0 >> 6) * 4096;
            #pragma unroll
            for (int msub = 0; msub < 4; msub++) {
                int gx = (msub & 1) * 2 + (g >> 1);
                int slotbase = (g & 1) * 4 + (msub >> 1) * 8;
                #pragma unroll
                for (int nsub = 0; nsub < 4; nsub++) {
                    s4v v = pk4bf(acc[msub][nsub][0], acc[msub][nsub][1],
                                  acc[msub][nsub][2], acc[msub][nsub][3]);
                    *(s4v*)(dst + nsub * 1024 + (gx * 16 + c) * 16 + slotbase) = v;
                }
            }
        }
    } else {
        int r0 = blockIdx.y * 128, j0 = 1024 + (blockIdx.x - 8) * 128;
        gemm_tile(xnb, Wt, r0, j0, acc);
        int R0 = r0 + rb * 64;            // token base
        int C0 = j0 + cb * 64;            // col base
        int hd = (C0 >> 6) & 7;
        int b = R0 >> 11, srow0 = R0 & 2047;
        unsigned short* dst = Vf + (size_t)(b * HEADS_ + hd) * S_ * DK_
                              + (size_t)(srow0 >> 6) * 4096;
        #pragma unroll
        for (int msub = 0; msub < 4; msub++)
            #pragma unroll
            for (int nsub = 0; nsub < 4; nsub++) {
                s4v v = pk4bf(acc[msub][nsub][0], acc[msub][nsub][1],
                              acc[msub][nsub][2], acc[msub][nsub][3]);
                *(s4v*)(dst + nsub * 1024 + (g * 16 + c) * 16 + msub * 4) = v;
            }
    }
}

// ---------------------------------------------------------------------------
// Kernel 3: flash attention. R11: L2-traffic halving via q-sharing.
// THEORY (fits all 10 rounds): attn is L2-BANDWIDTH-bound. Old structure:
// waves (qsub=0,kp) and (qsub=1,kp) read IDENTICAL K/V streams -> 1 MB/block
// x 1024 blocks = 1 GB L2 traffic; 1 GB / 59.5us = 16.8 TB/s ~= 50% of the
// 34.5 TB/s L2 ceiling. Explains: R1 HBM cut flat (volume through L2 same),
// R2 null (didn't dedup), R3/R8 small (latency only), R10 small (ops only).
// NEW: each wave owns ALL 64 q-rows x 1/4 of keys (kp 0..3, 512 keys =
// 16 halves). K/V read ONCE per block: 512 KB/block = 512 MB total (2x cut).
// Per-wave MFMA/exp2 work unchanged (2x q-tiles x 1/2 halves).
// Costs: VGPR ~210-230 (acc 64 + Q 32 + prefetch 64; (256,2) caps 256 —
// WRITE_SIZE 8.2MB is the no-spill checkpoint); 4->1 LDS combine 53 KB,
// [3][64][69] padding (69 mod 32 = 5, coprime -> conflict-free).
// Differs from R2 (regressed): R2 kept 32-row blocks + didn't cut traffic.
// ---------------------------------------------------------------------------
#define LOAD_KVH(pfx, hh) do {                                             \
    int kb_ = (hh) >> 1, h_ = (hh) & 1;                                    \
    const unsigned short* Kn_ = Kp + (size_t)kb_ * 4096;                   \
    const unsigned short* Vn_ = Vp + (size_t)kb_ * 4096;                   \
    pfx##k0lo = *(const s8v*)(Kn_ + (h_ * 2 + 0) * 1024);                  \
    pfx##k0hi = *(const s8v*)(Kn_ + (h_ * 2 + 0) * 1024 + 8);              \
    pfx##k1lo = *(const s8v*)(Kn_ + (h_ * 2 + 1) * 1024);                  \
    pfx##k1hi = *(const s8v*)(Kn_ + (h_ * 2 + 1) * 1024 + 8);              \
    pfx##mb0  = *(const float4*)(mbrow + kb_ * 64 + h_ * 32 + g * 4);      \
    pfx##mb1  = *(const float4*)(mbrow + kb_ * 64 + h_ * 32 + 16 + g * 4); \
    pfx##v0 = *(const s8v*)(Vn_ + 0 * 1024 + h_ * 8);                      \
    pfx##v1 = *(const s8v*)(Vn_ + 1 * 1024 + h_ * 8);                      \
    pfx##v2 = *(const s8v*)(Vn_ + 2 * 1024 + h_ * 8);                      \
    pfx##v3 = *(const s8v*)(Vn_ + 3 * 1024 + h_ * 8);                      \
} while (0)

// QK + softmax + PV for one 32-key half, FOUR 16-q tiles (A,B,C,D).
#define COMPUTE_HALF(pfx) do {                                                   \
    f4v bias0 = (f4v){pfx##mb0.x, pfx##mb0.y, pfx##mb0.z, pfx##mb0.w};           \
    f4v bias1 = (f4v){pfx##mb1.x, pfx##mb1.y, pfx##mb1.z, pfx##mb1.w};           \
    f4v sA0 = bias0, sA1 = bias1, sB0 = bias0, sB1 = bias1;                      \
    f4v sC0 = bias0, sC1 = bias1, sD0 = bias0, sD1 = bias1;                      \
    __builtin_amdgcn_s_setprio(1);                                               \
    sA0 = __builtin_amdgcn_mfma_f32_16x16x32_bf16(pfx##k0lo, qfA0, sA0, 0, 0, 0);\
    sA0 = __builtin_amdgcn_mfma_f32_16x16x32_bf16(pfx##k0hi, qfA1, sA0, 0, 0, 0);\
    sA1 = __builtin_amdgcn_mfma_f32_16x16x32_bf16(pfx##k1lo, qfA0, sA1, 0, 0, 0);\
    sA1 = __builtin_amdgcn_mfma_f32_16x16x32_bf16(pfx##k1hi, qfA1, sA1, 0, 0, 0);\
    sB0 = __builtin_amdgcn_mfma_f32_16x16x32_bf16(pfx##k0lo, qfB0, sB0, 0, 0, 0);\
    sB0 = __builtin_amdgcn_mfma_f32_16x16x32_bf16(pfx##k0hi, qfB1, sB0, 0, 0, 0);\
    sB1 = __builtin_amdgcn_mfma_f32_16x16x32_bf16(pfx##k1lo, qfB0, sB1, 0, 0, 0);\
    sB1 = __builtin_amdgcn_mfma_f32_16x16x32_bf16(pfx##k1hi, qfB1, sB1, 0, 0, 0);\
    sC0 = __builtin_amdgcn_mfma_f32_16x16x32_bf16(pfx##k0lo, qfC0, sC0, 0, 0, 0);\
    sC0 = __builtin_amdgcn_mfma_f32_16x16x32_bf16(pfx##k0hi, qfC1, sC0, 0, 0, 0);\
    sC1 = __builtin_amdgcn_mfma_f32_16x16x32_bf16(pfx##k1lo, qfC0, sC1, 0, 0, 0);\
    sC1 = __builtin_amdgcn_mfma_f32_16x16x32_bf16(pfx##k1hi, qfC1, sC1, 0, 0, 0);\
    sD0 = __builtin_amdgcn_mfma_f32_16x16x32_bf16(pfx##k0lo, qfD0, sD0, 0, 0, 0);\
    sD0 = __builtin_amdgcn_mfma_f32_16x16x32_bf16(pfx##k0hi, qfD1, sD0, 0, 0, 0);\
    sD1 = __builtin_amdgcn_mfma_f32_16x16x32_bf16(pfx##k1lo, qfD0, sD1, 0, 0, 0);\
    sD1 = __builtin_amdgcn_mfma_f32_16x16x32_bf16(pfx##k1hi, qfD1, sD1, 0, 0, 0);\
    __builtin_amdgcn_s_setprio(0);                                               \
    float pA0[4], pA1[4], pB0[4], pB1[4], pC0[4], pC1[4], pD0[4], pD1[4];        \
    _Pragma("unroll")                                                            \
    for (int r = 0; r < 4; r++) {                                                \
        pA0[r] = __builtin_amdgcn_exp2f(sA0[r]);                                 \
        pA1[r] = __builtin_amdgcn_exp2f(sA1[r]);                                 \
        pB0[r] = __builtin_amdgcn_exp2f(sB0[r]);                                 \
        pB1[r] = __builtin_amdgcn_exp2f(sB1[r]);                                 \
        pC0[r] = __builtin_amdgcn_exp2f(sC0[r]);                                 \
        pC1[r] = __builtin_amdgcn_exp2f(sC1[r]);                                 \
        pD0[r] = __builtin_amdgcn_exp2f(sD0[r]);                                 \
        pD1[r] = __builtin_amdgcn_exp2f(sD1[r]);                                 \
        lacA[r] += pA0[r] + pA1[r];                                              \
        lacB[r] += pB0[r] + pB1[r];                                              \
        lacC[r] += pC0[r] + pC1[r];                                              \
        lacD[r] += pD0[r] + pD1[r];                                              \
    }                                                                            \
    s8v pfa = __builtin_shufflevector(pk4bf(pA0[0], pA0[1], pA0[2], pA0[3]),     \
                                      pk4bf(pA1[0], pA1[1], pA1[2], pA1[3]),     \
                                      0, 1, 2, 3, 4, 5, 6, 7);                   \
    s8v pfb = __builtin_shufflevector(pk4bf(pB0[0], pB0[1], pB0[2], pB0[3]),     \
                                      pk4bf(pB1[0], pB1[1], pB1[2], pB1[3]),     \
                                      0, 1, 2, 3, 4, 5, 6, 7);                   \
    s8v pfc = __builtin_shufflevector(pk4bf(pC0[0], pC0[1], pC0[2], pC0[3]),     \
                                      pk4bf(pC1[0], pC1[1], pC1[2], pC1[3]),     \
                                      0, 1, 2, 3, 4, 5, 6, 7);                   \
    s8v pfd = __builtin_shufflevector(pk4bf(pD0[0], pD0[1], pD0[2], pD0[3]),     \
                                      pk4bf(pD1[0], pD1[1], pD1[2], pD1[3]),     \
                                      0, 1, 2, 3, 4, 5, 6, 7);                   \
    __builtin_amdgcn_s_setprio(1);                                               \
    accA[0] = __builtin_amdgcn_mfma_f32_16x16x32_bf16(pfx##v0, pfa, accA[0], 0, 0, 0); \
    accB[0] = __builtin_amdgcn_mfma_f32_16x16x32_bf16(pfx##v0, pfb, accB[0], 0, 0, 0); \
    accC[0] = __builtin_amdgcn_mfma_f32_16x16x32_bf16(pfx##v0, pfc, accC[0], 0, 0, 0); \
    accD[0] = __builtin_amdgcn_mfma_f32_16x16x32_bf16(pfx##v0, pfd, accD[0], 0, 0, 0); \
    accA[1] = __builtin_amdgcn_mfma_f32_16x16x32_bf16(pfx##v1, pfa, accA[1], 0, 0, 0); \
    accB[1] = __builtin_amdgcn_mfma_f32_16x16x32_bf16(pfx##v1, pfb, accB[1], 0, 0, 0); \
    accC[1] = __builtin_amdgcn_mfma_f32_16x16x32_bf16(pfx##v1, pfc, accC[1], 0, 0, 0); \
    accD[1] = __builtin_amdgcn_mfma_f32_16x16x32_bf16(pfx##v1, pfd, accD[1], 0, 0, 0); \
    accA[2] = __builtin_amdgcn_mfma_f32_16x16x32_bf16(pfx##v2, pfa, accA[2], 0, 0, 0); \
    accB[2] = __builtin_amdgcn_mfma_f32_16x16x32_bf16(pfx##v2, pfb, accB[2], 0, 0, 0); \
    accC[2] = __builtin_amdgcn_mfma_f32_16x16x32_bf16(pfx##v2, pfc, accC[2], 0, 0, 0); \
    accD[2] = __builtin_amdgcn_mfma_f32_16x16x32_bf16(pfx##v2, pfd, accD[2], 0, 0, 0); \
    accA[3] = __builtin_amdgcn_mfma_f32_16x16x32_bf16(pfx##v3, pfa, accA[3], 0, 0, 0); \
    accB[3] = __builtin_amdgcn_mfma_f32_16x16x32_bf16(pfx##v3, pfb, accB[3], 0, 0, 0); \
    accC[3] = __builtin_amdgcn_mfma_f32_16x16x32_bf16(pfx##v3, pfc, accC[3], 0, 0, 0); \
    accD[3] = __builtin_amdgcn_mfma_f32_16x16x32_bf16(pfx##v3, pfd, accD[3], 0, 0, 0); \
    __builtin_amdgcn_s_setprio(0);                                               \
} while (0)

__global__ __launch_bounds__(256, 2) void attn_kernel(
        const unsigned short* __restrict__ Qb,
        const unsigned short* __restrict__ Kf,
        const unsigned short* __restrict__ Vf,
        const float* __restrict__ mb,
        unsigned short* __restrict__ hb) {
    // combine buffer: [src wave-1][lane][4 tiles x (16 acc + 1 l)], pad 69
    __shared__ float red[3][64][69];     // 53 KB

    int kp = threadIdx.x >> 6;           // keypart: 0..3 (512 keys each)
    int L  = threadIdx.x & 63;
    int c  = L & 15;            // q within 16-q tile
    int g  = L >> 4;            // quad

    // XCD head-partition swizzle (gridDim = (32, 32), x fastest).
    unsigned wgid = blockIdx.x + blockIdx.y * 32u;
    unsigned xcd  = wgid & 7u;           // HW XCD for this block (round-robin)
    unsigned idx  = wgid >> 3;           // 0..127 within this XCD
    int bh = (int)(xcd + (idx >> 5) * 8u);   // heads {xcd, xcd+8, xcd+16, xcd+24}
    int qt = (int)(idx & 31u);               // 64-row q-tile within the head
    int b  = bh >> 3, n = bh & 7;
    int q0 = qt * 64;                    // block owns q0..q0+63; wave owns ALL

    const unsigned short* Qbase = Qb + (size_t)bh * S_ * DK_;
    const unsigned short* Kp = Kf + (size_t)bh * S_ * DK_ + (size_t)kp * 8 * 4096 + L * 16;
    const unsigned short* Vp = Vf + (size_t)bh * S_ * DK_ + (size_t)kp * 8 * 4096 + L * 16;
    const float* mbrow = mb + b * S_ + kp * 512;

    // Q fragments for 4 tiles (A: rows q0+c, B: +16, C: +32, D: +48)
    s8v qfA0 = *(const s8v*)(Qbase + (size_t)(q0 + c) * DK_ + g * 8);
    s8v qfA1 = *(const s8v*)(Qbase + (size_t)(q0 + c) * DK_ + 32 + g * 8);
    s8v qfB0 = *(const s8v*)(Qbase + (size_t)(q0 + 16 + c) * DK_ + g * 8);
    s8v qfB1 = *(const s8v*)(Qbase + (size_t)(q0 + 16 + c) * DK_ + 32 + g * 8);
    s8v qfC0 = *(const s8v*)(Qbase + (size_t)(q0 + 32 + c) * DK_ + g * 8);
    s8v qfC1 = *(const s8v*)(Qbase + (size_t)(q0 + 32 + c) * DK_ + 32 + g * 8);
    s8v qfD0 = *(const s8v*)(Qbase + (size_t)(q0 + 48 + c) * DK_ + g * 8);
    s8v qfD1 = *(const s8v*)(Qbase + (size_t)(q0 + 48 + c) * DK_ + 32 + g * 8);

    f4v accA[4], accB[4], accC[4], accD[4];   // O^T per tile
    #pragma unroll
    for (int i = 0; i < 4; i++) {
        accA[i] = (f4v){0.f, 0.f, 0.f, 0.f};
        accB[i] = (f4v){0.f, 0.f, 0.f, 0.f};
        accC[i] = (f4v){0.f, 0.f, 0.f, 0.f};
        accD[i] = (f4v){0.f, 0.f, 0.f, 0.f};
    }
    float lacA[4] = {0.f, 0.f, 0.f, 0.f};
    float lacB[4] = {0.f, 0.f, 0.f, 0.f};
    float lacC[4] = {0.f, 0.f, 0.f, 0.f};
    float lacD[4] = {0.f, 0.f, 0.f, 0.f};

    // two flattened prefetch buffers (a_*, b_*) — no struct, no lambda
    s8v a_k0lo, a_k0hi, a_k1lo, a_k1hi, a_v0, a_v1, a_v2, a_v3;
    float4 a_mb0, a_mb1;
    s8v b_k0lo, b_k0hi, b_k1lo, b_k1hi, b_v0, b_v1, b_v2, b_v3;
    float4 b_mb0, b_mb1;

    LOAD_KVH(a_, 0);
    for (int hh = 0; hh < 16; hh += 2) {     // 16 halves of 32 keys
        LOAD_KVH(b_, hh + 1);                // prefetch next half (K+bias+V)
        COMPUTE_HALF(a_);
        if (hh + 2 < 16) LOAD_KVH(a_, hh + 2);
        COMPUTE_HALF(b_);
    }

    float lA = (lacA[0] + lacA[1]) + (lacA[2] + lacA[3]);
    float lB = (lacB[0] + lacB[1]) + (lacB[2] + lacB[3]);
    float lC = (lacC[0] + lacC[1]) + (lacC[2] + lacC[3]);
    float lD = (lacD[0] + lacD[1]) + (lacD[2] + lacD[3]);
    lA += __shfl_xor(lA, 16, 64);
    lA += __shfl_xor(lA, 32, 64);
    lB += __shfl_xor(lB, 16, 64);
    lB += __shfl_xor(lB, 32, 64);
    lC += __shfl_xor(lC, 16, 64);
    lC += __shfl_xor(lC, 32, 64);
    lD += __shfl_xor(lD, 16, 64);
    lD += __shfl_xor(lD, 32, 64);

    // ---- combine keyparts through LDS: waves 1..3 write, wave 0 reduces ----
    if (kp >= 1) {
        float* dst = &red[kp - 1][L][0];
        #pragma unroll
        for (int d = 0; d < 4; d++) {
            #pragma unroll
            for (int r = 0; r < 4; r++) {
                dst[0 * 17 + d * 4 + r] = accA[d][r];
                dst[1 * 17 + d * 4 + r] = accB[d][r];
                dst[2 * 17 + d * 4 + r] = accC[d][r];
                dst[3 * 17 + d * 4 + r] = accD[d][r];
            }
        }
        dst[0 * 17 + 16] = lA;
        dst[1 * 17 + 16] = lB;
        dst[2 * 17 + 16] = lC;
        dst[3 * 17 + 16] = lD;
    }
    __syncthreads();
    if (kp == 0) {
        #pragma unroll
        for (int w = 0; w < 3; w++) {
            const float* s = &red[w][L][0];
            #pragma unroll
            for (int d = 0; d < 4; d++) {
                #pragma unroll
                for (int r = 0; r < 4; r++) {
                    accA[d][r] += s[0 * 17 + d * 4 + r];
                    accB[d][r] += s[1 * 17 + d * 4 + r];
                    accC[d][r] += s[2 * 17 + d * 4 + r];
                    accD[d][r] += s[3 * 17 + d * 4 + r];
                }
            }
            lA += s[0 * 17 + 16];
            lB += s[1 * 17 + 16];
            lC += s[2 * 17 + 16];
            lD += s[3 * 17 + 16];
        }
        float invA = 1.f / lA, invB = 1.f / lB;
        float invC = 1.f / lC, invD = 1.f / lD;
        unsigned short* hpA = hb + (size_t)(b * S_ + q0 + c) * H_ + n * DK_ + g * 4;
        unsigned short* hpB = hpA + (size_t)16 * H_;
        unsigned short* hpC = hpA + (size_t)32 * H_;
        unsigned short* hpD = hpA + (size_t)48 * H_;
        #pragma unroll
        for (int ds = 0; ds < 4; ds++) {
            *(s4v*)(hpA + ds * 16) = pk4bf(accA[ds][0] * invA, accA[ds][1] * invA,
                                           accA[ds][2] * invA, accA[ds][3] * invA);
            *(s4v*)(hpB + ds * 16) = pk4bf(accB[ds][0] * invB, accB[ds][1] * invB,
                                           accB[ds][2] * invB, accB[ds][3] * invB);
            *(s4v*)(hpC + ds * 16) = pk4bf(accC[ds][0] * invC, accC[ds][1] * invC,
                                           accC[ds][2] * invC, accC[ds][3] * invC);
            *(s4v*)(hpD + ds * 16) = pk4bf(accD[ds][0] * invD, accD[ds][1] * invD,
                                           accD[ds][2] * invD, accD[ds][3] * invD);
        }
    }
}

// ---------------------------------------------------------------------------
// Kernel 4: out = (hb @ Wot^T + xnb) * mask. Residual from bf16 xnb.
// ---------------------------------------------------------------------------
__global__ __launch_bounds__(256) void out_gemm(
        const unsigned short* __restrict__ hb,
        const unsigned short* __restrict__ Wot,
        const unsigned short* __restrict__ xnb, const int* __restrict__ mask,
        float* __restrict__ out) {
    f4v acc[4][4];
    int r0 = blockIdx.y * 128, j0 = blockIdx.x * 128;
    gemm_tile(hb, Wot, r0, j0, acc);
    int t = threadIdx.x;
    int wv = t >> 6, L = t & 63, c = L & 15, g = L >> 4;
    int mrow = r0 + (wv & 1) * 64 + g * 4;
    int ncol = j0 + (wv >> 1) * 64 + c;
    #pragma unroll
    for (int msub = 0; msub < 4; msub++) {
        #pragma unroll
        for (int rr = 0; rr < 4; rr++) {
            int row = mrow + msub * 16 + rr;
            float mf = (float)mask[row];
            #pragma unroll
            for (int nsub = 0; nsub < 4; nsub++) {
                int col = ncol + nsub * 16;
                size_t o = (size_t)row * H_ + col;
                out[o] = (acc[msub][nsub][rr] + bf2f(xnb[o])) * mf;
            }
        }
    }
}

// ---------------------------------------------------------------------------
extern "C" void kernel_launch(void* const* d_in, const int* in_sizes, int n_in,
                              void* d_out, int out_size, void* d_ws, size_t ws_size,
                              hipStream_t stream) {
    const float* x     = (const float*)d_in[0];
    const int*   mask  = (const int*)d_in[1];
    const float* Wq    = (const float*)d_in[2];
    const float* Wk    = (const float*)d_in[3];
    const float* Wv    = (const float*)d_in[4];
    const float* Wo    = (const float*)d_in[5];
    const float* gamma = (const float*)d_in[6];
    const float* beta  = (const float*)d_in[7];
    float* out = (float*)d_out;

    size_t nelem = (size_t)NROWS_ * H_;   // 4M elements
    char* ws = (char*)d_ws;
    unsigned short* xnb = (unsigned short*)ws; ws += nelem * 2;   // 8 MB
    unsigned short* hb  = (unsigned short*)ws; ws += nelem * 2;   // 8 MB
    unsigned short* Qb  = (unsigned short*)ws; ws += nelem * 2;   // 8 MB
    unsigned short* Kf  = (unsigned short*)ws; ws += nelem * 2;   // 8 MB
    unsigned short* Vf  = (unsigned short*)ws; ws += nelem * 2;   // 8 MB
    unsigned short* Wt  = (unsigned short*)ws; ws += (size_t)2048 * 512 * 2; // 2 MB
    float*          mbp = (float*)ws;                             // 32 KB

    prep_kernel<<<3072, 256, 0, stream>>>(
        x, gamma, beta, mask, Wq, Wk, Wv, Wo, xnb, mbp, Wt);
    qkv_gemm<<<dim3(12, 64), 256, 0, stream>>>(xnb, Wt, Qb, Kf, Vf);
    attn_kernel<<<dim3(S_ / 64, B_ * HEADS_), 256, 0, stream>>>(
        Qb, Kf, Vf, mbp, hb);
    out_gemm<<<dim3(4, 64), 256, 0, stream>>>(
        hb, Wt + (size_t)1536 * 512, xnb, mask, out);
}

// Round 12
// 179.123 us; speedup vs baseline: 1.1522x; 1.1522x over previous
//
#include <hip/hip_runtime.h>
#include <hip/hip_bf16.h>
#include <math.h>

#define B_ 4
#define S_ 2048
#define H_ 512
#define HEADS_ 8
#define DK_ 64
#define NROWS_ (B_*S_)          // 8192
#define LN_EPS_ 1e-5f
#define NEG_INF_ -1e30f
// Q pre-scale: 1/sqrt(DK) * log2(e)  (softmax done in exp2 domain)
#define QSCALE_ (0.125f * 1.44269504088896f)

typedef short s8v __attribute__((ext_vector_type(8)));   // 8 bf16 (4 VGPRs)
typedef short s4v __attribute__((ext_vector_type(4)));   // 4 bf16 (2 VGPRs)
typedef float f4v __attribute__((ext_vector_type(4)));

typedef __attribute__((address_space(1))) unsigned int gu32_t;
typedef __attribute__((address_space(3))) unsigned int lu32_t;

__device__ __forceinline__ unsigned short f2bf(float f) {
    unsigned int u = __float_as_uint(f);
    u += 0x7FFFu + ((u >> 16) & 1u);     // round-to-nearest-even
    return (unsigned short)(u >> 16);
}

__device__ __forceinline__ float bf2f(unsigned short u) {
    return __uint_as_float((unsigned int)u << 16);
}

__device__ __forceinline__ s4v pk4bf(float a, float b, float c, float d) {
    union { __hip_bfloat162 h[2]; s4v v; } u;
    u.h[0] = __float22bfloat162_rn(float2{a, b});
    u.h[1] = __float22bfloat162_rn(float2{c, d});
    return u.v;
}

// ---------------------------------------------------------------------------
// Kernel 1: PREP = LayerNorm (blocks 0..2047) + weight transpose (2048..3071).
// ---------------------------------------------------------------------------
__global__ __launch_bounds__(256) void prep_kernel(
        const float* __restrict__ x, const float* __restrict__ gamma,
        const float* __restrict__ beta, const int* __restrict__ mask,
        const float* __restrict__ Wq, const float* __restrict__ Wk,
        const float* __restrict__ Wv, const float* __restrict__ Wo,
        unsigned short* __restrict__ xnb, float* __restrict__ mb,
        unsigned short* __restrict__ Wt) {
    int bx = blockIdx.x;
    if (bx < 2048) {                       // ---------------- LayerNorm
        int row  = bx * 4 + (threadIdx.x >> 6);
        int lane = threadIdx.x & 63;
        const float4* xr = (const float4*)(x + (size_t)row * H_ + lane * 8);
        float4 a = xr[0], d = xr[1];
        float s  = (a.x + a.y) + (a.z + a.w) + (d.x + d.y) + (d.z + d.w);
        float ss = (a.x*a.x + a.y*a.y) + (a.z*a.z + a.w*a.w)
                 + (d.x*d.x + d.y*d.y) + (d.z*d.z + d.w*d.w);
        #pragma unroll
        for (int i = 1; i < 64; i <<= 1) {
            s  += __shfl_xor(s, i, 64);
            ss += __shfl_xor(ss, i, 64);
        }
        float mu  = s * (1.f / 512.f);
        float var = ss * (1.f / 512.f) - mu * mu;
        float rstd = rsqrtf(var + LN_EPS_);
        if (lane == 0) mb[row] = mask[row] ? 0.f : NEG_INF_;
        const float4* gp = (const float4*)(gamma + lane * 8);
        const float4* bp = (const float4*)(beta + lane * 8);
        float4 g0 = gp[0], g1 = gp[1], b0 = bp[0], b1 = bp[1];
        float4 y0, y1;
        y0.x = (a.x - mu) * rstd * g0.x + b0.x;
        y0.y = (a.y - mu) * rstd * g0.y + b0.y;
        y0.z = (a.z - mu) * rstd * g0.z + b0.z;
        y0.w = (a.w - mu) * rstd * g0.w + b0.w;
        y1.x = (d.x - mu) * rstd * g1.x + b1.x;
        y1.y = (d.y - mu) * rstd * g1.y + b1.y;
        y1.z = (d.z - mu) * rstd * g1.z + b1.z;
        y1.w = (d.w - mu) * rstd * g1.w + b1.w;
        union { s4v h[2]; s8v v; } pk;
        pk.h[0] = pk4bf(y0.x, y0.y, y0.z, y0.w);
        pk.h[1] = pk4bf(y1.x, y1.y, y1.z, y1.w);
        *(s8v*)(xnb + (size_t)row * H_ + lane * 8) = pk.v;
    } else {                               // ---------------- weight transpose
        __shared__ float tile[32][33];
        int wid = bx - 2048;
        const float* src;
        int ld, drow, k0, c0;
        float scale = 1.f;
        if (wid < 768) {
            int z = wid >> 5, rem = wid & 31;
            int cx = rem & 1, ky = rem >> 1;
            k0 = ky * 32; c0 = cx * 32;
            int zw = z >> 3, head = z & 7;
            const float* W = (zw == 0) ? Wq : (zw == 1) ? Wk : Wv;
            if (zw == 0) scale = QSCALE_;
            src = W + (size_t)head * H_ * DK_;
            ld = DK_;
            drow = zw * 512 + head * 64;
        } else {
            int rem = wid - 768;
            int cx = rem & 15, ky = rem >> 4;
            k0 = ky * 32; c0 = cx * 32;
            src = Wo; ld = H_; drow = 1536;
        }
        int tx = threadIdx.x & 31, ty = threadIdx.x >> 5;
        #pragma unroll
        for (int i = 0; i < 4; i++)
            tile[ty * 4 + i][tx] = src[(size_t)(k0 + ty * 4 + i) * ld + c0 + tx];
        __syncthreads();
        #pragma unroll
        for (int i = 0; i < 4; i++) {
            int cc = ty * 4 + i;
            Wt[(size_t)(drow + c0 + cc) * 512 + k0 + tx] = f2bf(tile[tx][cc] * scale);
        }
    }
}

// ---------------------------------------------------------------------------
// Shared MFMA GEMM tile loop. Depth-2 pipeline, 3 LDS buffer pairs (48 KB),
// vmcnt(8) steady state (R5). Total-neutral vs R3 but harmless; kept.
// ---------------------------------------------------------------------------
__device__ __forceinline__ void gemm_tile(
        const unsigned short* __restrict__ A,
        const unsigned short* __restrict__ Bt,
        int r0, int j0, f4v acc[4][4]) {
    __shared__ unsigned short As[3 * 128 * 32];   // [buf][row][k32], 8 KB each
    __shared__ unsigned short Bs[3 * 128 * 32];
    int t = threadIdx.x;
    int wv = t >> 6, L = t & 63, c = L & 15, g = L >> 4;
    int m_base = (wv & 1) * 64, n_base = (wv >> 1) * 64;
    #pragma unroll
    for (int i = 0; i < 4; i++)
        #pragma unroll
        for (int j = 0; j < 4; j++) acc[i][j] = (f4v){0.f, 0.f, 0.f, 0.f};

    // wave wv stages 32 rows (16B units uu = wv*128 + i*64 + L): 4 loads/wave
    auto stage = [&](int buf, int k0) {
        #pragma unroll
        for (int i = 0; i < 2; i++) {
            int uu = wv * 128 + i * 64 + L;
            int row = uu >> 2, k16 = uu & 3;
            __builtin_amdgcn_global_load_lds(
                (const gu32_t*)(A + (size_t)(r0 + row) * 512 + k0 + k16 * 8),
                (lu32_t*)(As + buf * 4096 + (size_t)(wv * 128 + i * 64) * 8), 16, 0, 0);
            __builtin_amdgcn_global_load_lds(
                (const gu32_t*)(Bt + (size_t)(j0 + row) * 512 + k0 + k16 * 8),
                (lu32_t*)(Bs + buf * 4096 + (size_t)(wv * 128 + i * 64) * 8), 16, 0, 0);
        }
    };

    auto compute = [&](int buf) {
        s8v a[4], b[4];
        #pragma unroll
        for (int i = 0; i < 4; i++)
            a[i] = *(const s8v*)(As + buf * 4096 + (size_t)(m_base + i * 16 + c) * 32 + g * 8);
        #pragma unroll
        for (int j = 0; j < 4; j++)
            b[j] = *(const s8v*)(Bs + buf * 4096 + (size_t)(n_base + j * 16 + c) * 32 + g * 8);
        #pragma unroll
        for (int i = 0; i < 4; i++)
            #pragma unroll
            for (int j = 0; j < 4; j++)
                acc[i][j] = __builtin_amdgcn_mfma_f32_16x16x32_bf16(
                    a[i], b[j], acc[i][j], 0, 0, 0);
    };

    stage(0, 0);
    stage(1, 32);
    #pragma unroll
    for (int s = 0; s < 14; ++s) {          // halves 0..13; stage halves 2..15
        stage((s + 2) % 3, (s + 2) * 32);
        __asm__ volatile("s_waitcnt vmcnt(8)" ::: "memory");  // own half-s done
        __builtin_amdgcn_s_barrier();                         // all half-s done
        compute(s % 3);
        __builtin_amdgcn_s_barrier();       // all reads of buf[s%3] done
    }
    __asm__ volatile("s_waitcnt vmcnt(4)" ::: "memory");      // half 14 done
    __builtin_amdgcn_s_barrier();
    compute(14 % 3);
    __builtin_amdgcn_s_barrier();
    __asm__ volatile("s_waitcnt vmcnt(0)" ::: "memory");      // half 15 done
    __builtin_amdgcn_s_barrier();
    compute(15 % 3);
}

// ---------------------------------------------------------------------------
// Kernel 2: QKV GEMM (epilogues unchanged).
// ---------------------------------------------------------------------------
__global__ __launch_bounds__(256) void qkv_gemm(
        const unsigned short* __restrict__ xnb,
        const unsigned short* __restrict__ Wt,
        unsigned short* __restrict__ Qb, unsigned short* __restrict__ Kf,
        unsigned short* __restrict__ Vf) {
    f4v acc[4][4];
    int t = threadIdx.x;
    int wv = t >> 6, L = t & 63, c = L & 15, g = L >> 4;
    int rb = wv & 1, cb = wv >> 1;
    if (blockIdx.x < 8) {
        int m0 = blockIdx.x * 128, n0 = blockIdx.y * 128;
        gemm_tile(Wt, xnb, m0, n0, acc);
        int R0 = m0 + rb * 64;            // Wt-row base (64-aligned, one head)
        int C0 = n0 + cb * 64;            // token base (64-aligned)
        int hd = (R0 >> 6) & 7;
        int b  = C0 >> 11, srow0 = C0 & 2047;
        size_t bhbase = (size_t)(b * HEADS_ + hd) * S_ * DK_;
        if (R0 < 512) {                   // ---- Q: row-major (token, dk)
            #pragma unroll
            for (int msub = 0; msub < 4; msub++) {
                int dk4 = msub * 16 + g * 4;
                #pragma unroll
                for (int nsub = 0; nsub < 4; nsub++) {
                    int tok = srow0 + nsub * 16 + c;
                    s4v v = pk4bf(acc[msub][nsub][0], acc[msub][nsub][1],
                                  acc[msub][nsub][2], acc[msub][nsub][3]);
                    *(s4v*)(Qb + bhbase + (size_t)tok * DK_ + dk4) = v;
                }
            }
        } else {                          // ---- K: fragment-major
            unsigned short* dst = Kf + bhbase + (size_t)(srow0 >> 6) * 4096;
            #pragma unroll
            for (int msub = 0; msub < 4; msub++) {
                int gx = (msub & 1) * 2 + (g >> 1);
                int slotbase = (g & 1) * 4 + (msub >> 1) * 8;
                #pragma unroll
                for (int nsub = 0; nsub < 4; nsub++) {
                    s4v v = pk4bf(acc[msub][nsub][0], acc[msub][nsub][1],
                                  acc[msub][nsub][2], acc[msub][nsub][3]);
                    *(s4v*)(dst + nsub * 1024 + (gx * 16 + c) * 16 + slotbase) = v;
                }
            }
        }
    } else {
        int r0 = blockIdx.y * 128, j0 = 1024 + (blockIdx.x - 8) * 128;
        gemm_tile(xnb, Wt, r0, j0, acc);
        int R0 = r0 + rb * 64;            // token base
        int C0 = j0 + cb * 64;            // col base
        int hd = (C0 >> 6) & 7;
        int b = R0 >> 11, srow0 = R0 & 2047;
        unsigned short* dst = Vf + (size_t)(b * HEADS_ + hd) * S_ * DK_
                              + (size_t)(srow0 >> 6) * 4096;
        #pragma unroll
        for (int msub = 0; msub < 4; msub++)
            #pragma unroll
            for (int nsub = 0; nsub < 4; nsub++) {
                s4v v = pk4bf(acc[msub][nsub][0], acc[msub][nsub][1],
                              acc[msub][nsub][2], acc[msub][nsub][3]);
                *(s4v*)(dst + nsub * 1024 + (g * 16 + c) * 16 + msub * 4) = v;
            }
    }
}

// ---------------------------------------------------------------------------
// Kernel 3: flash attention. R12: q-share retained, SPILL MECHANISM removed.
// R11's 4-tile q-share halved L2 traffic as designed but the allocator
// capped VGPR at the 128 quantum (despite (256,2) permitting 256) and
// spilled ~35MB/dispatch (WRITE 8.2->42.8MB, attn 91us). Fixes:
//  1. __launch_bounds__(256, 1): ceiling 512 VGPR. Expected alloc ~200 ->
//     2 waves/SIMD = 8 waves/CU = 2 blocks/CU = today's measured residency.
//  2. V dropped from prefetch buffers (-32 VGPR): with 4 tiles, each half
//     has 16 QK MFMAs + 32 exp2 (~300cy) between V's issue (top of
//     COMPUTE_HALF) and PV's first use — V self-covers. Prefetch = K+bias.
// Checkpoints: VGPR 160-240 (not 128), WRITE ~8.2MB. If spill-free and
// attn >= 55us -> L2-BW theory falsified -> revert to R10, declare plateau.
// ---------------------------------------------------------------------------
#define LOAD_KH(pfx, hh) do {                                              \
    int kb_ = (hh) >> 1, h_ = (hh) & 1;                                    \
    const unsigned short* Kn_ = Kp + (size_t)kb_ * 4096;                   \
    pfx##k0lo = *(const s8v*)(Kn_ + (h_ * 2 + 0) * 1024);                  \
    pfx##k0hi = *(const s8v*)(Kn_ + (h_ * 2 + 0) * 1024 + 8);              \
    pfx##k1lo = *(const s8v*)(Kn_ + (h_ * 2 + 1) * 1024);                  \
    pfx##k1hi = *(const s8v*)(Kn_ + (h_ * 2 + 1) * 1024 + 8);              \
    pfx##mb0  = *(const float4*)(mbrow + kb_ * 64 + h_ * 32 + g * 4);      \
    pfx##mb1  = *(const float4*)(mbrow + kb_ * 64 + h_ * 32 + 16 + g * 4); \
} while (0)

// QK + softmax + PV for one 32-key half, FOUR 16-q tiles (A,B,C,D).
// V loads issue at the top — covered by 16 QK MFMAs + 32 exp2 before use.
#define COMPUTE_HALF(pfx, hh) do {                                               \
    const unsigned short* Vn_ = Vp + (size_t)((hh) >> 1) * 4096 + ((hh) & 1) * 8;\
    s8v vv0 = *(const s8v*)(Vn_ + 0 * 1024);                                     \
    s8v vv1 = *(const s8v*)(Vn_ + 1 * 1024);                                     \
    s8v vv2 = *(const s8v*)(Vn_ + 2 * 1024);                                     \
    s8v vv3 = *(const s8v*)(Vn_ + 3 * 1024);                                     \
    f4v bias0 = (f4v){pfx##mb0.x, pfx##mb0.y, pfx##mb0.z, pfx##mb0.w};           \
    f4v bias1 = (f4v){pfx##mb1.x, pfx##mb1.y, pfx##mb1.z, pfx##mb1.w};           \
    f4v sA0 = bias0, sA1 = bias1, sB0 = bias0, sB1 = bias1;                      \
    f4v sC0 = bias0, sC1 = bias1, sD0 = bias0, sD1 = bias1;                      \
    __builtin_amdgcn_s_setprio(1);                                               \
    sA0 = __builtin_amdgcn_mfma_f32_16x16x32_bf16(pfx##k0lo, qfA0, sA0, 0, 0, 0);\
    sA0 = __builtin_amdgcn_mfma_f32_16x16x32_bf16(pfx##k0hi, qfA1, sA0, 0, 0, 0);\
    sA1 = __builtin_amdgcn_mfma_f32_16x16x32_bf16(pfx##k1lo, qfA0, sA1, 0, 0, 0);\
    sA1 = __builtin_amdgcn_mfma_f32_16x16x32_bf16(pfx##k1hi, qfA1, sA1, 0, 0, 0);\
    sB0 = __builtin_amdgcn_mfma_f32_16x16x32_bf16(pfx##k0lo, qfB0, sB0, 0, 0, 0);\
    sB0 = __builtin_amdgcn_mfma_f32_16x16x32_bf16(pfx##k0hi, qfB1, sB0, 0, 0, 0);\
    sB1 = __builtin_amdgcn_mfma_f32_16x16x32_bf16(pfx##k1lo, qfB0, sB1, 0, 0, 0);\
    sB1 = __builtin_amdgcn_mfma_f32_16x16x32_bf16(pfx##k1hi, qfB1, sB1, 0, 0, 0);\
    sC0 = __builtin_amdgcn_mfma_f32_16x16x32_bf16(pfx##k0lo, qfC0, sC0, 0, 0, 0);\
    sC0 = __builtin_amdgcn_mfma_f32_16x16x32_bf16(pfx##k0hi, qfC1, sC0, 0, 0, 0);\
    sC1 = __builtin_amdgcn_mfma_f32_16x16x32_bf16(pfx##k1lo, qfC0, sC1, 0, 0, 0);\
    sC1 = __builtin_amdgcn_mfma_f32_16x16x32_bf16(pfx##k1hi, qfC1, sC1, 0, 0, 0);\
    sD0 = __builtin_amdgcn_mfma_f32_16x16x32_bf16(pfx##k0lo, qfD0, sD0, 0, 0, 0);\
    sD0 = __builtin_amdgcn_mfma_f32_16x16x32_bf16(pfx##k0hi, qfD1, sD0, 0, 0, 0);\
    sD1 = __builtin_amdgcn_mfma_f32_16x16x32_bf16(pfx##k1lo, qfD0, sD1, 0, 0, 0);\
    sD1 = __builtin_amdgcn_mfma_f32_16x16x32_bf16(pfx##k1hi, qfD1, sD1, 0, 0, 0);\
    __builtin_amdgcn_s_setprio(0);                                               \
    float pA0[4], pA1[4], pB0[4], pB1[4], pC0[4], pC1[4], pD0[4], pD1[4];        \
    _Pragma("unroll")                                                            \
    for (int r = 0; r < 4; r++) {                                                \
        pA0[r] = __builtin_amdgcn_exp2f(sA0[r]);                                 \
        pA1[r] = __builtin_amdgcn_exp2f(sA1[r]);                                 \
        pB0[r] = __builtin_amdgcn_exp2f(sB0[r]);                                 \
        pB1[r] = __builtin_amdgcn_exp2f(sB1[r]);                                 \
        pC0[r] = __builtin_amdgcn_exp2f(sC0[r]);                                 \
        pC1[r] = __builtin_amdgcn_exp2f(sC1[r]);                                 \
        pD0[r] = __builtin_amdgcn_exp2f(sD0[r]);                                 \
        pD1[r] = __builtin_amdgcn_exp2f(sD1[r]);                                 \
        lacA[r] += pA0[r] + pA1[r];                                              \
        lacB[r] += pB0[r] + pB1[r];                                              \
        lacC[r] += pC0[r] + pC1[r];                                              \
        lacD[r] += pD0[r] + pD1[r];                                              \
    }                                                                            \
    s8v pfa = __builtin_shufflevector(pk4bf(pA0[0], pA0[1], pA0[2], pA0[3]),     \
                                      pk4bf(pA1[0], pA1[1], pA1[2], pA1[3]),     \
                                      0, 1, 2, 3, 4, 5, 6, 7);                   \
    s8v pfb = __builtin_shufflevector(pk4bf(pB0[0], pB0[1], pB0[2], pB0[3]),     \
                                      pk4bf(pB1[0], pB1[1], pB1[2], pB1[3]),     \
                                      0, 1, 2, 3, 4, 5, 6, 7);                   \
    s8v pfc = __builtin_shufflevector(pk4bf(pC0[0], pC0[1], pC0[2], pC0[3]),     \
                                      pk4bf(pC1[0], pC1[1], pC1[2], pC1[3]),     \
                                      0, 1, 2, 3, 4, 5, 6, 7);                   \
    s8v pfd = __builtin_shufflevector(pk4bf(pD0[0], pD0[1], pD0[2], pD0[3]),     \
                                      pk4bf(pD1[0], pD1[1], pD1[2], pD1[3]),     \
                                      0, 1, 2, 3, 4, 5, 6, 7);                   \
    __builtin_amdgcn_s_setprio(1);                                               \
    accA[0] = __builtin_amdgcn_mfma_f32_16x16x32_bf16(vv0, pfa, accA[0], 0, 0, 0); \
    accB[0] = __builtin_amdgcn_mfma_f32_16x16x32_bf16(vv0, pfb, accB[0], 0, 0, 0); \
    accC[0] = __builtin_amdgcn_mfma_f32_16x16x32_bf16(vv0, pfc, accC[0], 0, 0, 0); \
    accD[0] = __builtin_amdgcn_mfma_f32_16x16x32_bf16(vv0, pfd, accD[0], 0, 0, 0); \
    accA[1] = __builtin_amdgcn_mfma_f32_16x16x32_bf16(vv1, pfa, accA[1], 0, 0, 0); \
    accB[1] = __builtin_amdgcn_mfma_f32_16x16x32_bf16(vv1, pfb, accB[1], 0, 0, 0); \
    accC[1] = __builtin_amdgcn_mfma_f32_16x16x32_bf16(vv1, pfc, accC[1], 0, 0, 0); \
    accD[1] = __builtin_amdgcn_mfma_f32_16x16x32_bf16(vv1, pfd, accD[1], 0, 0, 0); \
    accA[2] = __builtin_amdgcn_mfma_f32_16x16x32_bf16(vv2, pfa, accA[2], 0, 0, 0); \
    accB[2] = __builtin_amdgcn_mfma_f32_16x16x32_bf16(vv2, pfb, accB[2], 0, 0, 0); \
    accC[2] = __builtin_amdgcn_mfma_f32_16x16x32_bf16(vv2, pfc, accC[2], 0, 0, 0); \
    accD[2] = __builtin_amdgcn_mfma_f32_16x16x32_bf16(vv2, pfd, accD[2], 0, 0, 0); \
    accA[3] = __builtin_amdgcn_mfma_f32_16x16x32_bf16(vv3, pfa, accA[3], 0, 0, 0); \
    accB[3] = __builtin_amdgcn_mfma_f32_16x16x32_bf16(vv3, pfb, accB[3], 0, 0, 0); \
    accC[3] = __builtin_amdgcn_mfma_f32_16x16x32_bf16(vv3, pfc, accC[3], 0, 0, 0); \
    accD[3] = __builtin_amdgcn_mfma_f32_16x16x32_bf16(vv3, pfd, accD[3], 0, 0, 0); \
    __builtin_amdgcn_s_setprio(0);                                               \
} while (0)

__global__ __launch_bounds__(256, 1) void attn_kernel(
        const unsigned short* __restrict__ Qb,
        const unsigned short* __restrict__ Kf,
        const unsigned short* __restrict__ Vf,
        const float* __restrict__ mb,
        unsigned short* __restrict__ hb) {
    // combine buffer: [src wave-1][lane][4 tiles x (16 acc + 1 l)], pad 69
    __shared__ float red[3][64][69];     // 53 KB

    int kp = threadIdx.x >> 6;           // keypart: 0..3 (512 keys each)
    int L  = threadIdx.x & 63;
    int c  = L & 15;            // q within 16-q tile
    int g  = L >> 4;            // quad

    // XCD head-partition swizzle (gridDim = (32, 32), x fastest).
    unsigned wgid = blockIdx.x + blockIdx.y * 32u;
    unsigned xcd  = wgid & 7u;           // HW XCD for this block (round-robin)
    unsigned idx  = wgid >> 3;           // 0..127 within this XCD
    int bh = (int)(xcd + (idx >> 5) * 8u);   // heads {xcd, xcd+8, xcd+16, xcd+24}
    int qt = (int)(idx & 31u);               // 64-row q-tile within the head
    int b  = bh >> 3, n = bh & 7;
    int q0 = qt * 64;                    // block owns q0..q0+63; wave owns ALL

    const unsigned short* Qbase = Qb + (size_t)bh * S_ * DK_;
    const unsigned short* Kp = Kf + (size_t)bh * S_ * DK_ + (size_t)kp * 8 * 4096 + L * 16;
    const unsigned short* Vp = Vf + (size_t)bh * S_ * DK_ + (size_t)kp * 8 * 4096 + L * 16;
    const float* mbrow = mb + b * S_ + kp * 512;

    // Q fragments for 4 tiles (A: rows q0+c, B: +16, C: +32, D: +48)
    s8v qfA0 = *(const s8v*)(Qbase + (size_t)(q0 + c) * DK_ + g * 8);
    s8v qfA1 = *(const s8v*)(Qbase + (size_t)(q0 + c) * DK_ + 32 + g * 8);
    s8v qfB0 = *(const s8v*)(Qbase + (size_t)(q0 + 16 + c) * DK_ + g * 8);
    s8v qfB1 = *(const s8v*)(Qbase + (size_t)(q0 + 16 + c) * DK_ + 32 + g * 8);
    s8v qfC0 = *(const s8v*)(Qbase + (size_t)(q0 + 32 + c) * DK_ + g * 8);
    s8v qfC1 = *(const s8v*)(Qbase + (size_t)(q0 + 32 + c) * DK_ + 32 + g * 8);
    s8v qfD0 = *(const s8v*)(Qbase + (size_t)(q0 + 48 + c) * DK_ + g * 8);
    s8v qfD1 = *(const s8v*)(Qbase + (size_t)(q0 + 48 + c) * DK_ + 32 + g * 8);

    f4v accA[4], accB[4], accC[4], accD[4];   // O^T per tile
    #pragma unroll
    for (int i = 0; i < 4; i++) {
        accA[i] = (f4v){0.f, 0.f, 0.f, 0.f};
        accB[i] = (f4v){0.f, 0.f, 0.f, 0.f};
        accC[i] = (f4v){0.f, 0.f, 0.f, 0.f};
        accD[i] = (f4v){0.f, 0.f, 0.f, 0.f};
    }
    float lacA[4] = {0.f, 0.f, 0.f, 0.f};
    float lacB[4] = {0.f, 0.f, 0.f, 0.f};
    float lacC[4] = {0.f, 0.f, 0.f, 0.f};
    float lacD[4] = {0.f, 0.f, 0.f, 0.f};

    // two flattened K+bias prefetch buffers (a_*, b_*) — no struct, no lambda
    s8v a_k0lo, a_k0hi, a_k1lo, a_k1hi;
    float4 a_mb0, a_mb1;
    s8v b_k0lo, b_k0hi, b_k1lo, b_k1hi;
    float4 b_mb0, b_mb1;

    LOAD_KH(a_, 0);
    for (int hh = 0; hh < 16; hh += 2) {     // 16 halves of 32 keys
        LOAD_KH(b_, hh + 1);                 // prefetch next half (K+bias)
        COMPUTE_HALF(a_, hh);
        if (hh + 2 < 16) LOAD_KH(a_, hh + 2);
        COMPUTE_HALF(b_, hh + 1);
    }

    float lA = (lacA[0] + lacA[1]) + (lacA[2] + lacA[3]);
    float lB = (lacB[0] + lacB[1]) + (lacB[2] + lacB[3]);
    float lC = (lacC[0] + lacC[1]) + (lacC[2] + lacC[3]);
    float lD = (lacD[0] + lacD[1]) + (lacD[2] + lacD[3]);
    lA += __shfl_xor(lA, 16, 64);
    lA += __shfl_xor(lA, 32, 64);
    lB += __shfl_xor(lB, 16, 64);
    lB += __shfl_xor(lB, 32, 64);
    lC += __shfl_xor(lC, 16, 64);
    lC += __shfl_xor(lC, 32, 64);
    lD += __shfl_xor(lD, 16, 64);
    lD += __shfl_xor(lD, 32, 64);

    // ---- combine keyparts through LDS: waves 1..3 write, wave 0 reduces ----
    if (kp >= 1) {
        float* dst = &red[kp - 1][L][0];
        #pragma unroll
        for (int d = 0; d < 4; d++) {
            #pragma unroll
            for (int r = 0; r < 4; r++) {
                dst[0 * 17 + d * 4 + r] = accA[d][r];
                dst[1 * 17 + d * 4 + r] = accB[d][r];
                dst[2 * 17 + d * 4 + r] = accC[d][r];
                dst[3 * 17 + d * 4 + r] = accD[d][r];
            }
        }
        dst[0 * 17 + 16] = lA;
        dst[1 * 17 + 16] = lB;
        dst[2 * 17 + 16] = lC;
        dst[3 * 17 + 16] = lD;
    }
    __syncthreads();
    if (kp == 0) {
        #pragma unroll
        for (int w = 0; w < 3; w++) {
            const float* s = &red[w][L][0];
            #pragma unroll
            for (int d = 0; d < 4; d++) {
                #pragma unroll
                for (int r = 0; r < 4; r++) {
                    accA[d][r] += s[0 * 17 + d * 4 + r];
                    accB[d][r] += s[1 * 17 + d * 4 + r];
                    accC[d][r] += s[2 * 17 + d * 4 + r];
                    accD[d][r] += s[3 * 17 + d * 4 + r];
                }
            }
            lA += s[0 * 17 + 16];
            lB += s[1 * 17 + 16];
            lC += s[2 * 17 + 16];
            lD += s[3 * 17 + 16];
        }
        float invA = 1.f / lA, invB = 1.f / lB;
        float invC = 1.f / lC, invD = 1.f / lD;
        unsigned short* hpA = hb + (size_t)(b * S_ + q0 + c) * H_ + n * DK_ + g * 4;
        unsigned short* hpB = hpA + (size_t)16 * H_;
        unsigned short* hpC = hpA + (size_t)32 * H_;
        unsigned short* hpD = hpA + (size_t)48 * H_;
        #pragma unroll
        for (int ds = 0; ds < 4; ds++) {
            *(s4v*)(hpA + ds * 16) = pk4bf(accA[ds][0] * invA, accA[ds][1] * invA,
                                           accA[ds][2] * invA, accA[ds][3] * invA);
            *(s4v*)(hpB + ds * 16) = pk4bf(accB[ds][0] * invB, accB[ds][1] * invB,
                                           accB[ds][2] * invB, accB[ds][3] * invB);
            *(s4v*)(hpC + ds * 16) = pk4bf(accC[ds][0] * invC, accC[ds][1] * invC,
                                           accC[ds][2] * invC, accC[ds][3] * invC);
            *(s4v*)(hpD + ds * 16) = pk4bf(accD[ds][0] * invD, accD[ds][1] * invD,
                                           accD[ds][2] * invD, accD[ds][3] * invD);
        }
    }
}

// ---------------------------------------------------------------------------
// Kernel 4: out = (hb @ Wot^T + xnb) * mask. Residual from bf16 xnb.
// ---------------------------------------------------------------------------
__global__ __launch_bounds__(256) void out_gemm(
        const unsigned short* __restrict__ hb,
        const unsigned short* __restrict__ Wot,
        const unsigned short* __restrict__ xnb, const int* __restrict__ mask,
        float* __restrict__ out) {
    f4v acc[4][4];
    int r0 = blockIdx.y * 128, j0 = blockIdx.x * 128;
    gemm_tile(hb, Wot, r0, j0, acc);
    int t = threadIdx.x;
    int wv = t >> 6, L = t & 63, c = L & 15, g = L >> 4;
    int mrow = r0 + (wv & 1) * 64 + g * 4;
    int ncol = j0 + (wv >> 1) * 64 + c;
    #pragma unroll
    for (int msub = 0; msub < 4; msub++) {
        #pragma unroll
        for (int rr = 0; rr < 4; rr++) {
            int row = mrow + msub * 16 + rr;
            float mf = (float)mask[row];
            #pragma unroll
            for (int nsub = 0; nsub < 4; nsub++) {
                int col = ncol + nsub * 16;
                size_t o = (size_t)row * H_ + col;
                out[o] = (acc[msub][nsub][rr] + bf2f(xnb[o])) * mf;
            }
        }
    }
}

// ---------------------------------------------------------------------------
extern "C" void kernel_launch(void* const* d_in, const int* in_sizes, int n_in,
                              void* d_out, int out_size, void* d_ws, size_t ws_size,
                              hipStream_t stream) {
    const float* x     = (const float*)d_in[0];
    const int*   mask  = (const int*)d_in[1];
    const float* Wq    = (const float*)d_in[2];
    const float* Wk    = (const float*)d_in[3];
    const float* Wv    = (const float*)d_in[4];
    const float* Wo    = (const float*)d_in[5];
    const float* gamma = (const float*)d_in[6];
    const float* beta  = (const float*)d_in[7];
    float* out = (float*)d_out;

    size_t nelem = (size_t)NROWS_ * H_;   // 4M elements
    char* ws = (char*)d_ws;
    unsigned short* xnb = (unsigned short*)ws; ws += nelem * 2;   // 8 MB
    unsigned short* hb  = (unsigned short*)ws; ws += nelem * 2;   // 8 MB
    unsigned short* Qb  = (unsigned short*)ws; ws += nelem * 2;   // 8 MB
    unsigned short* Kf  = (unsigned short*)ws; ws += nelem * 2;   // 8 MB
    unsigned short* Vf  = (unsigned short*)ws; ws += nelem * 2;   // 8 MB
    unsigned short* Wt  = (unsigned short*)ws; ws += (size_t)2048 * 512 * 2; // 2 MB
    float*          mbp = (float*)ws;                             // 32 KB

    prep_kernel<<<3072, 256, 0, stream>>>(
        x, gamma, beta, mask, Wq, Wk, Wv, Wo, xnb, mbp, Wt);
    qkv_gemm<<<dim3(12, 64), 256, 0, stream>>>(xnb, Wt, Qb, Kf, Vf);
    attn_kernel<<<dim3(S_ / 64, B_ * HEADS_), 256, 0, stream>>>(
        Qb, Kf, Vf, mbp, hb);
    out_gemm<<<dim3(4, 64), 256, 0, stream>>>(
        hb, Wt + (size_t)1536 * 512, xnb, mask, out);
}

// Round 13
// 172.719 us; speedup vs baseline: 1.1949x; 1.0371x over previous
//
#include <hip/hip_runtime.h>
#include <hip/hip_bf16.h>
#include <math.h>

#define B_ 4
#define S_ 2048
#define H_ 512
#define HEADS_ 8
#define DK_ 64
#define NROWS_ (B_*S_)          // 8192
#define LN_EPS_ 1e-5f
#define NEG_INF_ -1e30f
// Q pre-scale: 1/sqrt(DK) * log2(e)  (softmax done in exp2 domain)
#define QSCALE_ (0.125f * 1.44269504088896f)

typedef short s8v __attribute__((ext_vector_type(8)));   // 8 bf16 (4 VGPRs)
typedef short s4v __attribute__((ext_vector_type(4)));   // 4 bf16 (2 VGPRs)
typedef float f4v __attribute__((ext_vector_type(4)));

typedef __attribute__((address_space(1))) unsigned int gu32_t;
typedef __attribute__((address_space(3))) unsigned int lu32_t;

__device__ __forceinline__ unsigned short f2bf(float f) {
    unsigned int u = __float_as_uint(f);
    u += 0x7FFFu + ((u >> 16) & 1u);     // round-to-nearest-even
    return (unsigned short)(u >> 16);
}

__device__ __forceinline__ float bf2f(unsigned short u) {
    return __uint_as_float((unsigned int)u << 16);
}

__device__ __forceinline__ s4v pk4bf(float a, float b, float c, float d) {
    union { __hip_bfloat162 h[2]; s4v v; } u;
    u.h[0] = __float22bfloat162_rn(float2{a, b});
    u.h[1] = __float22bfloat162_rn(float2{c, d});
    return u.v;
}

// ---------------------------------------------------------------------------
// Kernel 1: PREP = LayerNorm (blocks 0..2047) + weight transpose (2048..3071).
// ---------------------------------------------------------------------------
__global__ __launch_bounds__(256) void prep_kernel(
        const float* __restrict__ x, const float* __restrict__ gamma,
        const float* __restrict__ beta, const int* __restrict__ mask,
        const float* __restrict__ Wq, const float* __restrict__ Wk,
        const float* __restrict__ Wv, const float* __restrict__ Wo,
        unsigned short* __restrict__ xnb, float* __restrict__ mb,
        unsigned short* __restrict__ Wt) {
    int bx = blockIdx.x;
    if (bx < 2048) {                       // ---------------- LayerNorm
        int row  = bx * 4 + (threadIdx.x >> 6);
        int lane = threadIdx.x & 63;
        const float4* xr = (const float4*)(x + (size_t)row * H_ + lane * 8);
        float4 a = xr[0], d = xr[1];
        float s  = (a.x + a.y) + (a.z + a.w) + (d.x + d.y) + (d.z + d.w);
        float ss = (a.x*a.x + a.y*a.y) + (a.z*a.z + a.w*a.w)
                 + (d.x*d.x + d.y*d.y) + (d.z*d.z + d.w*d.w);
        #pragma unroll
        for (int i = 1; i < 64; i <<= 1) {
            s  += __shfl_xor(s, i, 64);
            ss += __shfl_xor(ss, i, 64);
        }
        float mu  = s * (1.f / 512.f);
        float var = ss * (1.f / 512.f) - mu * mu;
        float rstd = rsqrtf(var + LN_EPS_);
        if (lane == 0) mb[row] = mask[row] ? 0.f : NEG_INF_;
        const float4* gp = (const float4*)(gamma + lane * 8);
        const float4* bp = (const float4*)(beta + lane * 8);
        float4 g0 = gp[0], g1 = gp[1], b0 = bp[0], b1 = bp[1];
        float4 y0, y1;
        y0.x = (a.x - mu) * rstd * g0.x + b0.x;
        y0.y = (a.y - mu) * rstd * g0.y + b0.y;
        y0.z = (a.z - mu) * rstd * g0.z + b0.z;
        y0.w = (a.w - mu) * rstd * g0.w + b0.w;
        y1.x = (d.x - mu) * rstd * g1.x + b1.x;
        y1.y = (d.y - mu) * rstd * g1.y + b1.y;
        y1.z = (d.z - mu) * rstd * g1.z + b1.z;
        y1.w = (d.w - mu) * rstd * g1.w + b1.w;
        union { s4v h[2]; s8v v; } pk;
        pk.h[0] = pk4bf(y0.x, y0.y, y0.z, y0.w);
        pk.h[1] = pk4bf(y1.x, y1.y, y1.z, y1.w);
        *(s8v*)(xnb + (size_t)row * H_ + lane * 8) = pk.v;
    } else {                               // ---------------- weight transpose
        __shared__ float tile[32][33];
        int wid = bx - 2048;
        const float* src;
        int ld, drow, k0, c0;
        float scale = 1.f;
        if (wid < 768) {
            int z = wid >> 5, rem = wid & 31;
            int cx = rem & 1, ky = rem >> 1;
            k0 = ky * 32; c0 = cx * 32;
            int zw = z >> 3, head = z & 7;
            const float* W = (zw == 0) ? Wq : (zw == 1) ? Wk : Wv;
            if (zw == 0) scale = QSCALE_;
            src = W + (size_t)head * H_ * DK_;
            ld = DK_;
            drow = zw * 512 + head * 64;
        } else {
            int rem = wid - 768;
            int cx = rem & 15, ky = rem >> 4;
            k0 = ky * 32; c0 = cx * 32;
            src = Wo; ld = H_; drow = 1536;
        }
        int tx = threadIdx.x & 31, ty = threadIdx.x >> 5;
        #pragma unroll
        for (int i = 0; i < 4; i++)
            tile[ty * 4 + i][tx] = src[(size_t)(k0 + ty * 4 + i) * ld + c0 + tx];
        __syncthreads();
        #pragma unroll
        for (int i = 0; i < 4; i++) {
            int cc = ty * 4 + i;
            Wt[(size_t)(drow + c0 + cc) * 512 + k0 + tx] = f2bf(tile[tx][cc] * scale);
        }
    }
}

// ---------------------------------------------------------------------------
// Shared MFMA GEMM tile loop. Depth-2 pipeline, 3 LDS buffer pairs (48 KB),
// vmcnt(8) steady state (R5). Total-neutral vs R3 but harmless; kept.
// ---------------------------------------------------------------------------
__device__ __forceinline__ void gemm_tile(
        const unsigned short* __restrict__ A,
        const unsigned short* __restrict__ Bt,
        int r0, int j0, f4v acc[4][4]) {
    __shared__ unsigned short As[3 * 128 * 32];   // [buf][row][k32], 8 KB each
    __shared__ unsigned short Bs[3 * 128 * 32];
    int t = threadIdx.x;
    int wv = t >> 6, L = t & 63, c = L & 15, g = L >> 4;
    int m_base = (wv & 1) * 64, n_base = (wv >> 1) * 64;
    #pragma unroll
    for (int i = 0; i < 4; i++)
        #pragma unroll
        for (int j = 0; j < 4; j++) acc[i][j] = (f4v){0.f, 0.f, 0.f, 0.f};

    // wave wv stages 32 rows (16B units uu = wv*128 + i*64 + L): 4 loads/wave
    auto stage = [&](int buf, int k0) {
        #pragma unroll
        for (int i = 0; i < 2; i++) {
            int uu = wv * 128 + i * 64 + L;
            int row = uu >> 2, k16 = uu & 3;
            __builtin_amdgcn_global_load_lds(
                (const gu32_t*)(A + (size_t)(r0 + row) * 512 + k0 + k16 * 8),
                (lu32_t*)(As + buf * 4096 + (size_t)(wv * 128 + i * 64) * 8), 16, 0, 0);
            __builtin_amdgcn_global_load_lds(
                (const gu32_t*)(Bt + (size_t)(j0 + row) * 512 + k0 + k16 * 8),
                (lu32_t*)(Bs + buf * 4096 + (size_t)(wv * 128 + i * 64) * 8), 16, 0, 0);
        }
    };

    auto compute = [&](int buf) {
        s8v a[4], b[4];
        #pragma unroll
        for (int i = 0; i < 4; i++)
            a[i] = *(const s8v*)(As + buf * 4096 + (size_t)(m_base + i * 16 + c) * 32 + g * 8);
        #pragma unroll
        for (int j = 0; j < 4; j++)
            b[j] = *(const s8v*)(Bs + buf * 4096 + (size_t)(n_base + j * 16 + c) * 32 + g * 8);
        #pragma unroll
        for (int i = 0; i < 4; i++)
            #pragma unroll
            for (int j = 0; j < 4; j++)
                acc[i][j] = __builtin_amdgcn_mfma_f32_16x16x32_bf16(
                    a[i], b[j], acc[i][j], 0, 0, 0);
    };

    stage(0, 0);
    stage(1, 32);
    #pragma unroll
    for (int s = 0; s < 14; ++s) {          // halves 0..13; stage halves 2..15
        stage((s + 2) % 3, (s + 2) * 32);
        __asm__ volatile("s_waitcnt vmcnt(8)" ::: "memory");  // own half-s done
        __builtin_amdgcn_s_barrier();                         // all half-s done
        compute(s % 3);
        __builtin_amdgcn_s_barrier();       // all reads of buf[s%3] done
    }
    __asm__ volatile("s_waitcnt vmcnt(4)" ::: "memory");      // half 14 done
    __builtin_amdgcn_s_barrier();
    compute(14 % 3);
    __builtin_amdgcn_s_barrier();
    __asm__ volatile("s_waitcnt vmcnt(0)" ::: "memory");      // half 15 done
    __builtin_amdgcn_s_barrier();
    compute(15 % 3);
}

// ---------------------------------------------------------------------------
// Kernel 2: QKV GEMM (epilogues unchanged).
// ---------------------------------------------------------------------------
__global__ __launch_bounds__(256) void qkv_gemm(
        const unsigned short* __restrict__ xnb,
        const unsigned short* __restrict__ Wt,
        unsigned short* __restrict__ Qb, unsigned short* __restrict__ Kf,
        unsigned short* __restrict__ Vf) {
    f4v acc[4][4];
    int t = threadIdx.x;
    int wv = t >> 6, L = t & 63, c = L & 15, g = L >> 4;
    int rb = wv & 1, cb = wv >> 1;
    if (blockIdx.x < 8) {
        int m0 = blockIdx.x * 128, n0 = blockIdx.y * 128;
        gemm_tile(Wt, xnb, m0, n0, acc);
        int R0 = m0 + rb * 64;            // Wt-row base (64-aligned, one head)
        int C0 = n0 + cb * 64;            // token base (64-aligned)
        int hd = (R0 >> 6) & 7;
        int b  = C0 >> 11, srow0 = C0 & 2047;
        size_t bhbase = (size_t)(b * HEADS_ + hd) * S_ * DK_;
        if (R0 < 512) {                   // ---- Q: row-major (token, dk)
            #pragma unroll
            for (int msub = 0; msub < 4; msub++) {
                int dk4 = msub * 16 + g * 4;
                #pragma unroll
                for (int nsub = 0; nsub < 4; nsub++) {
                    int tok = srow0 + nsub * 16 + c;
                    s4v v = pk4bf(acc[msub][nsub][0], acc[msub][nsub][1],
                                  acc[msub][nsub][2], acc[msub][nsub][3]);
                    *(s4v*)(Qb + bhbase + (size_t)tok * DK_ + dk4) = v;
                }
            }
        } else {                          // ---- K: fragment-major
            unsigned short* dst = Kf + bhbase + (size_t)(srow0 >> 6) * 4096;
            #pragma unroll
            for (int msub = 0; msub < 4; msub++) {
                int gx = (msub & 1) * 2 + (g >> 1);
                int slotbase = (g & 1) * 4 + (msub >> 1) * 8;
                #pragma unroll
                for (int nsub = 0; nsub < 4; nsub++) {
                    s4v v = pk4bf(acc[msub][nsub][0], acc[msub][nsub][1],
                                  acc[msub][nsub][2], acc[msub][nsub][3]);
                    *(s4v*)(dst + nsub * 1024 + (gx * 16 + c) * 16 + slotbase) = v;
                }
            }
        }
    } else {
        int r0 = blockIdx.y * 128, j0 = 1024 + (blockIdx.x - 8) * 128;
        gemm_tile(xnb, Wt, r0, j0, acc);
        int R0 = r0 + rb * 64;            // token base
        int C0 = j0 + cb * 64;            // col base
        int hd = (C0 >> 6) & 7;
        int b = R0 >> 11, srow0 = R0 & 2047;
        unsigned short* dst = Vf + (size_t)(b * HEADS_ + hd) * S_ * DK_
                              + (size_t)(srow0 >> 6) * 4096;
        #pragma unroll
        for (int msub = 0; msub < 4; msub++)
            #pragma unroll
            for (int nsub = 0; nsub < 4; nsub++) {
                s4v v = pk4bf(acc[msub][nsub][0], acc[msub][nsub][1],
                              acc[msub][nsub][2], acc[msub][nsub][3]);
                *(s4v*)(dst + nsub * 1024 + (g * 16 + c) * 16 + msub * 4) = v;
            }
    }
}

// ---------------------------------------------------------------------------
// Kernel 3: flash attention. R13 = REVERT to the measured best (R10,
// 59.5us attn / 173.8us total): 2-keypart x 2-qsub, full-KV register
// prefetch (flattened buffers, (256,2), VGPR 92, spill-free), PV via K=32
// MFMAs. History of falsified alternatives, with measured A/Bs:
//  - XCD head-partition swizzle (R1): FETCH 70->12.4MB, time flat. KEPT
//    (frees HBM for other kernels) but attn not HBM-bound.
//  - 4-way keypart TLP (R2): -25% (reduce tail + dup Q + bank conflicts).
//  - K/bias reg prefetch (R3): +3%. Full-KV prefetch spill-free (R8): +4%.
//  - (256,3) and struct/lambda prefetch (R7): SPILLS (WRITE 13.4MB) — the
//    two codegen hazards are register-ceiling quanta and non-flattened
//    aggregates; both must be avoided together (R8's fix).
//  - PV K=32 merge (R9/R10): +5%, MFMA count 24->16/half.
//  - L2-dedup q-share (R11 spilled; R12 spill-free VGPR 164): 66.4us >
//    59.5us -> L2-BW theory FALSIFIED (halved L2 bytes, worse time; TLP
//    loss + VALU overhead dominated).
// Conclusion: ~59.5us is this decomposition's plateau — no pipe saturated,
// residual is distributed load latency at low steady-state residency;
// every lever (traffic, TLP, ILP, instruction count) measured at <=5%.
// ---------------------------------------------------------------------------
#define LOAD_KVH(pfx, hh) do {                                             \
    int kb_ = (hh) >> 1, h_ = (hh) & 1;                                    \
    const unsigned short* Kn_ = Kp + (size_t)kb_ * 4096;                   \
    const unsigned short* Vn_ = Vp + (size_t)kb_ * 4096;                   \
    pfx##k0lo = *(const s8v*)(Kn_ + (h_ * 2 + 0) * 1024);                  \
    pfx##k0hi = *(const s8v*)(Kn_ + (h_ * 2 + 0) * 1024 + 8);              \
    pfx##k1lo = *(const s8v*)(Kn_ + (h_ * 2 + 1) * 1024);                  \
    pfx##k1hi = *(const s8v*)(Kn_ + (h_ * 2 + 1) * 1024 + 8);              \
    pfx##mb0  = *(const float4*)(mbrow + kb_ * 64 + h_ * 32 + g * 4);      \
    pfx##mb1  = *(const float4*)(mbrow + kb_ * 64 + h_ * 32 + 16 + g * 4); \
    pfx##v0 = *(const s8v*)(Vn_ + 0 * 1024 + h_ * 8);                      \
    pfx##v1 = *(const s8v*)(Vn_ + 1 * 1024 + h_ * 8);                      \
    pfx##v2 = *(const s8v*)(Vn_ + 2 * 1024 + h_ * 8);                      \
    pfx##v3 = *(const s8v*)(Vn_ + 3 * 1024 + h_ * 8);                      \
} while (0)

#define COMPUTE_HALF(pfx) do {                                                   \
    f4v bias0 = (f4v){pfx##mb0.x, pfx##mb0.y, pfx##mb0.z, pfx##mb0.w};           \
    f4v bias1 = (f4v){pfx##mb1.x, pfx##mb1.y, pfx##mb1.z, pfx##mb1.w};           \
    f4v sA0 = bias0, sA1 = bias1, sB0 = bias0, sB1 = bias1;                      \
    __builtin_amdgcn_s_setprio(1);                                               \
    sA0 = __builtin_amdgcn_mfma_f32_16x16x32_bf16(pfx##k0lo, qfA0, sA0, 0, 0, 0);\
    sA0 = __builtin_amdgcn_mfma_f32_16x16x32_bf16(pfx##k0hi, qfA1, sA0, 0, 0, 0);\
    sA1 = __builtin_amdgcn_mfma_f32_16x16x32_bf16(pfx##k1lo, qfA0, sA1, 0, 0, 0);\
    sA1 = __builtin_amdgcn_mfma_f32_16x16x32_bf16(pfx##k1hi, qfA1, sA1, 0, 0, 0);\
    sB0 = __builtin_amdgcn_mfma_f32_16x16x32_bf16(pfx##k0lo, qfB0, sB0, 0, 0, 0);\
    sB0 = __builtin_amdgcn_mfma_f32_16x16x32_bf16(pfx##k0hi, qfB1, sB0, 0, 0, 0);\
    sB1 = __builtin_amdgcn_mfma_f32_16x16x32_bf16(pfx##k1lo, qfB0, sB1, 0, 0, 0);\
    sB1 = __builtin_amdgcn_mfma_f32_16x16x32_bf16(pfx##k1hi, qfB1, sB1, 0, 0, 0);\
    __builtin_amdgcn_s_setprio(0);                                               \
    float pA0[4], pA1[4], pB0[4], pB1[4];                                        \
    _Pragma("unroll")                                                            \
    for (int r = 0; r < 4; r++) {                                                \
        pA0[r] = __builtin_amdgcn_exp2f(sA0[r]);                                 \
        pA1[r] = __builtin_amdgcn_exp2f(sA1[r]);                                 \
        pB0[r] = __builtin_amdgcn_exp2f(sB0[r]);                                 \
        pB1[r] = __builtin_amdgcn_exp2f(sB1[r]);                                 \
        lacA[r] += pA0[r] + pA1[r];                                              \
        lacB[r] += pB0[r] + pB1[r];                                              \
    }                                                                            \
    s4v pfA0 = pk4bf(pA0[0], pA0[1], pA0[2], pA0[3]);                            \
    s4v pfA1 = pk4bf(pA1[0], pA1[1], pA1[2], pA1[3]);                            \
    s4v pfB0 = pk4bf(pB0[0], pB0[1], pB0[2], pB0[3]);                            \
    s4v pfB1 = pk4bf(pB1[0], pB1[1], pB1[2], pB1[3]);                            \
    s8v pfa = __builtin_shufflevector(pfA0, pfA1, 0, 1, 2, 3, 4, 5, 6, 7);       \
    s8v pfb = __builtin_shufflevector(pfB0, pfB1, 0, 1, 2, 3, 4, 5, 6, 7);       \
    __builtin_amdgcn_s_setprio(1);                                               \
    accA[0] = __builtin_amdgcn_mfma_f32_16x16x32_bf16(pfx##v0, pfa, accA[0], 0, 0, 0); \
    accB[0] = __builtin_amdgcn_mfma_f32_16x16x32_bf16(pfx##v0, pfb, accB[0], 0, 0, 0); \
    accA[1] = __builtin_amdgcn_mfma_f32_16x16x32_bf16(pfx##v1, pfa, accA[1], 0, 0, 0); \
    accB[1] = __builtin_amdgcn_mfma_f32_16x16x32_bf16(pfx##v1, pfb, accB[1], 0, 0, 0); \
    accA[2] = __builtin_amdgcn_mfma_f32_16x16x32_bf16(pfx##v2, pfa, accA[2], 0, 0, 0); \
    accB[2] = __builtin_amdgcn_mfma_f32_16x16x32_bf16(pfx##v2, pfb, accB[2], 0, 0, 0); \
    accA[3] = __builtin_amdgcn_mfma_f32_16x16x32_bf16(pfx##v3, pfa, accA[3], 0, 0, 0); \
    accB[3] = __builtin_amdgcn_mfma_f32_16x16x32_bf16(pfx##v3, pfb, accB[3], 0, 0, 0); \
    __builtin_amdgcn_s_setprio(0);                                               \
} while (0)

__global__ __launch_bounds__(256, 2) void attn_kernel(
        const unsigned short* __restrict__ Qb,
        const unsigned short* __restrict__ Kf,
        const unsigned short* __restrict__ Vf,
        const float* __restrict__ mb,
        unsigned short* __restrict__ hb) {
    __shared__ float red[2][64][2][17];  // [qsub][lane][qgroup][16 acc + l]

    int wv   = threadIdx.x >> 6;
    int qsub = wv & 1;
    int kp   = wv >> 1;                  // keypart: 0 or 1
    int L  = threadIdx.x & 63;
    int c  = L & 15;            // q within 16-q tile
    int g  = L >> 4;            // quad

    // XCD head-partition swizzle (gridDim = (32, 32), x fastest).
    unsigned wgid = blockIdx.x + blockIdx.y * 32u;
    unsigned xcd  = wgid & 7u;           // HW XCD for this block (round-robin)
    unsigned idx  = wgid >> 3;           // 0..127 within this XCD
    int bh = (int)(xcd + (idx >> 5) * 8u);   // heads {xcd, xcd+8, xcd+16, xcd+24}
    int qt = (int)(idx & 31u);               // q-tile within the head
    int b  = bh >> 3, n = bh & 7;
    int q0 = qt * 64 + qsub * 32;        // wave owns q0..q0+31

    const unsigned short* Qbase = Qb + (size_t)bh * S_ * DK_;
    const unsigned short* Kp = Kf + (size_t)bh * S_ * DK_ + (size_t)kp * 16 * 4096 + L * 16;
    const unsigned short* Vp = Vf + (size_t)bh * S_ * DK_ + (size_t)kp * 16 * 4096 + L * 16;
    const float* mbrow = mb + b * S_ + kp * 1024;

    s8v qfA0 = *(const s8v*)(Qbase + (size_t)(q0 + c) * DK_ + g * 8);
    s8v qfA1 = *(const s8v*)(Qbase + (size_t)(q0 + c) * DK_ + 32 + g * 8);
    s8v qfB0 = *(const s8v*)(Qbase + (size_t)(q0 + 16 + c) * DK_ + g * 8);
    s8v qfB1 = *(const s8v*)(Qbase + (size_t)(q0 + 16 + c) * DK_ + 32 + g * 8);

    f4v accA[4], accB[4];       // O^T: d = dsub*16 + g*4 + r
    #pragma unroll
    for (int i = 0; i < 4; i++) {
        accA[i] = (f4v){0.f, 0.f, 0.f, 0.f};
        accB[i] = (f4v){0.f, 0.f, 0.f, 0.f};
    }
    float lacA[4] = {0.f, 0.f, 0.f, 0.f};
    float lacB[4] = {0.f, 0.f, 0.f, 0.f};

    // two flattened prefetch buffers (a_*, b_*) — no struct, no lambda
    s8v a_k0lo, a_k0hi, a_k1lo, a_k1hi, a_v0, a_v1, a_v2, a_v3;
    float4 a_mb0, a_mb1;
    s8v b_k0lo, b_k0hi, b_k1lo, b_k1hi, b_v0, b_v1, b_v2, b_v3;
    float4 b_mb0, b_mb1;

    LOAD_KVH(a_, 0);
    for (int hh = 0; hh < 32; hh += 2) {     // statically-unrolled 2-step swap
        LOAD_KVH(b_, hh + 1);                // prefetch next half (K+bias+V)
        COMPUTE_HALF(a_);
        if (hh + 2 < 32) LOAD_KVH(a_, hh + 2);
        COMPUTE_HALF(b_);
    }

    float lA = (lacA[0] + lacA[1]) + (lacA[2] + lacA[3]);
    float lB = (lacB[0] + lacB[1]) + (lacB[2] + lacB[3]);
    lA += __shfl_xor(lA, 16, 64);
    lA += __shfl_xor(lA, 32, 64);
    lB += __shfl_xor(lB, 16, 64);
    lB += __shfl_xor(lB, 32, 64);

    // ---- combine keyparts through LDS ----
    if (kp == 1) {
        #pragma unroll
        for (int d = 0; d < 4; d++) {
            #pragma unroll
            for (int r = 0; r < 4; r++) {
                red[qsub][L][0][d * 4 + r] = accA[d][r];
                red[qsub][L][1][d * 4 + r] = accB[d][r];
            }
        }
        red[qsub][L][0][16] = lA;
        red[qsub][L][1][16] = lB;
    }
    __syncthreads();
    if (kp == 0) {
        const float* srcA = &red[qsub][L][0][0];
        const float* srcB = &red[qsub][L][1][0];
        float invA = 1.f / (lA + srcA[16]);
        float invB = 1.f / (lB + srcB[16]);
        unsigned short* hpA = hb + (size_t)(b * S_ + q0 + c) * H_ + n * DK_ + g * 4;
        unsigned short* hpB = hpA + (size_t)16 * H_;
        #pragma unroll
        for (int ds = 0; ds < 4; ds++) {
            s4v oA = pk4bf((accA[ds][0] + srcA[ds * 4 + 0]) * invA,
                           (accA[ds][1] + srcA[ds * 4 + 1]) * invA,
                           (accA[ds][2] + srcA[ds * 4 + 2]) * invA,
                           (accA[ds][3] + srcA[ds * 4 + 3]) * invA);
            *(s4v*)(hpA + ds * 16) = oA;
            s4v oB = pk4bf((accB[ds][0] + srcB[ds * 4 + 0]) * invB,
                           (accB[ds][1] + srcB[ds * 4 + 1]) * invB,
                           (accB[ds][2] + srcB[ds * 4 + 2]) * invB,
                           (accB[ds][3] + srcB[ds * 4 + 3]) * invB);
            *(s4v*)(hpB + ds * 16) = oB;
        }
    }
}

// ---------------------------------------------------------------------------
// Kernel 4: out = (hb @ Wot^T + xnb) * mask. Residual from bf16 xnb.
// ---------------------------------------------------------------------------
__global__ __launch_bounds__(256) void out_gemm(
        const unsigned short* __restrict__ hb,
        const unsigned short* __restrict__ Wot,
        const unsigned short* __restrict__ xnb, const int* __restrict__ mask,
        float* __restrict__ out) {
    f4v acc[4][4];
    int r0 = blockIdx.y * 128, j0 = blockIdx.x * 128;
    gemm_tile(hb, Wot, r0, j0, acc);
    int t = threadIdx.x;
    int wv = t >> 6, L = t & 63, c = L & 15, g = L >> 4;
    int mrow = r0 + (wv & 1) * 64 + g * 4;
    int ncol = j0 + (wv >> 1) * 64 + c;
    #pragma unroll
    for (int msub = 0; msub < 4; msub++) {
        #pragma unroll
        for (int rr = 0; rr < 4; rr++) {
            int row = mrow + msub * 16 + rr;
            float mf = (float)mask[row];
            #pragma unroll
            for (int nsub = 0; nsub < 4; nsub++) {
                int col = ncol + nsub * 16;
                size_t o = (size_t)row * H_ + col;
                out[o] = (acc[msub][nsub][rr] + bf2f(xnb[o])) * mf;
            }
        }
    }
}

// ---------------------------------------------------------------------------
extern "C" void kernel_launch(void* const* d_in, const int* in_sizes, int n_in,
                              void* d_out, int out_size, void* d_ws, size_t ws_size,
                              hipStream_t stream) {
    const float* x     = (const float*)d_in[0];
    const int*   mask  = (const int*)d_in[1];
    const float* Wq    = (const float*)d_in[2];
    const float* Wk    = (const float*)d_in[3];
    const float* Wv    = (const float*)d_in[4];
    const float* Wo    = (const float*)d_in[5];
    const float* gamma = (const float*)d_in[6];
    const float* beta  = (const float*)d_in[7];
    float* out = (float*)d_out;

    size_t nelem = (size_t)NROWS_ * H_;   // 4M elements
    char* ws = (char*)d_ws;
    unsigned short* xnb = (unsigned short*)ws; ws += nelem * 2;   // 8 MB
    unsigned short* hb  = (unsigned short*)ws; ws += nelem * 2;   // 8 MB
    unsigned short* Qb  = (unsigned short*)ws; ws += nelem * 2;   // 8 MB
    unsigned short* Kf  = (unsigned short*)ws; ws += nelem * 2;   // 8 MB
    unsigned short* Vf  = (unsigned short*)ws; ws += nelem * 2;   // 8 MB
    unsigned short* Wt  = (unsigned short*)ws; ws += (size_t)2048 * 512 * 2; // 2 MB
    float*          mbp = (float*)ws;                             // 32 KB

    prep_kernel<<<3072, 256, 0, stream>>>(
        x, gamma, beta, mask, Wq, Wk, Wv, Wo, xnb, mbp, Wt);
    qkv_gemm<<<dim3(12, 64), 256, 0, stream>>>(xnb, Wt, Qb, Kf, Vf);
    attn_kernel<<<dim3(S_ / 64, B_ * HEADS_), 256, 0, stream>>>(
        Qb, Kf, Vf, mbp, hb);
    out_gemm<<<dim3(4, 64), 256, 0, stream>>>(
        hb, Wt + (size_t)1536 * 512, xnb, mask, out);
}